// Round 2
// baseline (1170.622 us; speedup 1.0000x reference)
//
#include <hip/hip_runtime.h>
#include <hip/hip_bf16.h>
#include <stdint.h>

#define B_    2
#define T_    2048
#define EMB_  2048
#define NH_   16
#define NKV_  4
#define HD_   128
#define MLPD_ 8192
#define WIN_  1024
#define BT_   (B_ * T_)     // 4096 rows
#define QKVN_ 3072          // NH*HD + NKV*HD + NKV*HD

typedef __bf16 bf16;
typedef __bf16 bf16x8 __attribute__((ext_vector_type(8)));
typedef float  f32x4  __attribute__((ext_vector_type(4)));

__device__ __forceinline__ bf16 f2b(float f) {
  __hip_bfloat16 h = __float2bfloat16(f);
  return *reinterpret_cast<bf16*>(&h);
}
__device__ __forceinline__ float b2f(bf16 b) {
  __hip_bfloat16 h = *reinterpret_cast<__hip_bfloat16*>(&b);
  return __bfloat162float(h);
}

__device__ __forceinline__ void load_lds16(const void* g, void* l) {
  __builtin_amdgcn_global_load_lds(
      (const __attribute__((address_space(1))) void*)g,
      (__attribute__((address_space(3))) void*)l, 16, 0, 0);
}

// ---------- transpose f32 [R][C] -> bf16 [C][R] ----------
__global__ __launch_bounds__(256) void transpose_kernel(
    const float* __restrict__ in, bf16* __restrict__ out, int R, int C)
{
  __shared__ float tile[32][33];
  const int tx = threadIdx.x, ty = threadIdx.y;  // blockDim (32,8)
  const int c0 = blockIdx.x * 32, r0 = blockIdx.y * 32;
  #pragma unroll
  for (int i = 0; i < 32; i += 8)
    tile[ty + i][tx] = in[(long)(r0 + ty + i) * C + c0 + tx];
  __syncthreads();
  #pragma unroll
  for (int i = 0; i < 32; i += 8)
    out[(long)(c0 + ty + i) * R + r0 + tx] = f2b(tile[tx][ty + i]);
}

// ---------- RMSNorm: f32 row -> bf16 row ----------
__global__ __launch_bounds__(256) void rmsnorm_kernel(
    const float* __restrict__ x, const float* __restrict__ scale,
    bf16* __restrict__ out)
{
  const long row = blockIdx.x;
  const float* xr = x + row * EMB_;
  bf16* orow = out + row * EMB_;
  const float4 v0 = ((const float4*)xr)[threadIdx.x];
  const float4 v1 = ((const float4*)xr)[threadIdx.x + 256];
  float ss = v0.x*v0.x + v0.y*v0.y + v0.z*v0.z + v0.w*v0.w
           + v1.x*v1.x + v1.y*v1.y + v1.z*v1.z + v1.w*v1.w;
  #pragma unroll
  for (int off = 32; off >= 1; off >>= 1) ss += __shfl_xor(ss, off, 64);
  __shared__ float red[4];
  if ((threadIdx.x & 63) == 0) red[threadIdx.x >> 6] = ss;
  __syncthreads();
  const float tot = red[0] + red[1] + red[2] + red[3];
  const float rs = rsqrtf(tot * (1.0f / EMB_) + 1e-6f);
  const float4 s0 = ((const float4*)scale)[threadIdx.x];
  const float4 s1 = ((const float4*)scale)[threadIdx.x + 256];
  const int c0 = threadIdx.x * 4;
  orow[c0 + 0]    = f2b(v0.x * rs * (1.0f + s0.x));
  orow[c0 + 1]    = f2b(v0.y * rs * (1.0f + s0.y));
  orow[c0 + 2]    = f2b(v0.z * rs * (1.0f + s0.z));
  orow[c0 + 3]    = f2b(v0.w * rs * (1.0f + s0.w));
  orow[c0 + 1024] = f2b(v1.x * rs * (1.0f + s1.x));
  orow[c0 + 1025] = f2b(v1.y * rs * (1.0f + s1.y));
  orow[c0 + 1026] = f2b(v1.z * rs * (1.0f + s1.z));
  orow[c0 + 1027] = f2b(v1.w * rs * (1.0f + s1.w));
}

// ---------- GEMM: C[M][N] = A[M][K] * Bt[N][K]^T, bf16 in, f32 acc ----------
// EPI 0: bf16 out.  EPI 1: f32 out = acc + res (res may alias out, same-elem RMW).
// EPI 2: bf16 out = silu(gate)*acc.
template <int EPI>
__global__ __launch_bounds__(256) void gemm_kernel(
    const bf16* __restrict__ A, const bf16* __restrict__ Bt,
    void* __restrict__ out, const float* __restrict__ res,
    const bf16* __restrict__ gatev, int M, int N, int K)
{
  __shared__ __align__(16) bf16 As[128 * 32];
  __shared__ __align__(16) bf16 Bs[128 * 32];
  const int tid  = threadIdx.x;
  const int wave = tid >> 6, lane = tid & 63;
  const int bm = blockIdx.y << 7, bn = blockIdx.x << 7;
  const int wm = (wave & 1) << 6, wn = (wave >> 1) << 6;
  const int l16 = lane & 15, quad = lane >> 4;
  const int srow = lane >> 2, scol = (lane & 3) << 3;

  const bf16* Ap = A  + (long)(bm + wave * 32 + srow) * K + scol;
  const bf16* Bp = Bt + (long)(bn + wave * 32 + srow) * K + scol;
  char* ldsA = (char*)As + wave * 2048;
  char* ldsB = (char*)Bs + wave * 2048;

  f32x4 acc[4][4] = {};

  for (int k0 = 0; k0 < K; k0 += 32) {
    __syncthreads();
    #pragma unroll
    for (int j = 0; j < 2; ++j) {
      load_lds16(Ap + (long)j * 16 * K + k0, ldsA + j * 1024);
      load_lds16(Bp + (long)j * 16 * K + k0, ldsB + j * 1024);
    }
    __syncthreads();
    bf16x8 af[4], bfr[4];
    #pragma unroll
    for (int i = 0; i < 4; ++i) {
      af[i]  = *(const bf16x8*)&As[(wm + i * 16 + l16) * 32 + quad * 8];
      bfr[i] = *(const bf16x8*)&Bs[(wn + i * 16 + l16) * 32 + quad * 8];
    }
    #pragma unroll
    for (int mb = 0; mb < 4; ++mb)
      #pragma unroll
      for (int nb = 0; nb < 4; ++nb)
        acc[mb][nb] = __builtin_amdgcn_mfma_f32_16x16x32_bf16(af[mb], bfr[nb], acc[mb][nb], 0, 0, 0);
  }

  const int crow = bm + wm + (quad << 2);
  const int ccol = bn + wn + l16;
  #pragma unroll
  for (int mb = 0; mb < 4; ++mb)
    #pragma unroll
    for (int nb = 0; nb < 4; ++nb)
      #pragma unroll
      for (int r = 0; r < 4; ++r) {
        const long idx = (long)(crow + mb * 16 + r) * N + (ccol + nb * 16);
        const float v = acc[mb][nb][r];
        if (EPI == 0) {
          ((bf16*)out)[idx] = f2b(v);
        } else if (EPI == 1) {
          ((float*)out)[idx] = v + res[idx];
        } else {
          const float g = b2f(gatev[idx]);
          ((bf16*)out)[idx] = f2b(v * (g / (1.0f + __expf(-g))));
        }
      }
}

// ---------- RoPE + layout: qkv bf16 [BT][3072] -> Q [B][NH][T][HD],
//            K [B][NKV][T][HD], V^T [B][NKV][HD][T] ----------
__global__ __launch_bounds__(256) void rope_kernel(
    const bf16* __restrict__ qkv, bf16* __restrict__ Q,
    bf16* __restrict__ K, bf16* __restrict__ VT)
{
  const int t = blockIdx.x, b = blockIdx.y;
  const bf16* row = qkv + (long)(b * T_ + t) * QKVN_;
  const float tf = (float)t;  // positions = t (segment_ids all-ones, cur_ind=0)
  for (int idx = threadIdx.x; idx < NH_ * HD_; idx += 256) {
    const int head = idx >> 7, hd = idx & 127;
    const float v = b2f(row[idx]);
    float o;
    if (hd < 64) {
      const int j = hd & 31;
      const float ang = tf * expf(-(float)j * 0.28782313662425574f); // ln(1e4)/32
      const float sn = sinf(ang), cs = cosf(ang);
      o = (hd < 32) ? (v * cs - b2f(row[idx + 32]) * sn)
                    : (v * cs + b2f(row[idx - 32]) * sn);
    } else o = v;
    Q[((long)(b * NH_ + head) * T_ + t) * HD_ + hd] = f2b(o);
  }
  for (int idx = threadIdx.x; idx < NKV_ * HD_; idx += 256) {
    const int kv = idx >> 7, hd = idx & 127;
    const float v = b2f(row[NH_ * HD_ + idx]);
    float o;
    if (hd < 64) {
      const int j = hd & 31;
      const float ang = tf * expf(-(float)j * 0.28782313662425574f);
      const float sn = sinf(ang), cs = cosf(ang);
      o = (hd < 32) ? (v * cs - b2f(row[NH_ * HD_ + idx + 32]) * sn)
                    : (v * cs + b2f(row[NH_ * HD_ + idx - 32]) * sn);
    } else o = v;
    K[((long)(b * NKV_ + kv) * T_ + t) * HD_ + hd] = f2b(o);
  }
  for (int idx = threadIdx.x; idx < NKV_ * HD_; idx += 256) {
    const int kv = idx >> 7, vd = idx & 127;
    VT[((long)(b * NKV_ + kv) * HD_ + vd) * T_ + t] = row[(NH_ + NKV_) * HD_ + idx];
  }
}

// ---------- Flash attention: 64-row Q tile per block, window 1024, sink ----------
__global__ __launch_bounds__(256) void attn_kernel(
    const bf16* __restrict__ Q, const bf16* __restrict__ Kg,
    const bf16* __restrict__ VTg, const float* __restrict__ sink,
    bf16* __restrict__ attnb)
{
  __shared__ __align__(16) bf16 Qs[64 * 136];   // padded: stride 136 elems (272B)
  __shared__ __align__(16) bf16 Ks[64 * 136];
  __shared__ __align__(16) bf16 Vs[128 * 72];   // V^T tile, stride 72 (144B)
  __shared__ __align__(16) bf16 Ps[64 * 72];    // P round-trip C-layout -> A-layout

  const int qt = blockIdx.x;
  const int bh = blockIdx.y;
  const int b = bh >> 4, h = bh & 15;
  const int kvh = h >> 2;            // GQA: 4 q-heads per kv-head
  const int t0 = qt * 64;
  const int tid = threadIdx.x;
  const int wave = tid >> 6, lane = tid & 63;
  const int quad = lane >> 4, l16 = lane & 15;

  const bf16* Qp = Q + ((long)(b * NH_ + h) * T_ + t0) * HD_;
  #pragma unroll
  for (int c = tid; c < 1024; c += 256) {
    const int r = c >> 4, cc = (c & 15) << 3;
    *(uint4*)&Qs[r * 136 + cc] = *(const uint4*)&Qp[r * HD_ + cc];
  }

  float m_i[4], l_i[4];
  const float sb = sink[h];
  #pragma unroll
  for (int r = 0; r < 4; ++r) { m_i[r] = sb; l_i[r] = 1.0f; }  // sink column
  f32x4 Oacc[8] = {};

  const int st_lo = (qt > 16) ? (qt - 16) : 0;
  for (int st = st_lo; st <= qt; ++st) {
    const int s0 = st * 64;
    __syncthreads();
    const bf16* Kp = Kg + ((long)(b * NKV_ + kvh) * T_ + s0) * HD_;
    #pragma unroll
    for (int c = tid; c < 1024; c += 256) {
      const int r = c >> 4, cc = (c & 15) << 3;
      *(uint4*)&Ks[r * 136 + cc] = *(const uint4*)&Kp[r * HD_ + cc];
    }
    const bf16* Vp = VTg + (long)(b * NKV_ + kvh) * HD_ * T_ + s0;
    #pragma unroll
    for (int c = tid; c < 1024; c += 256) {
      const int r = c >> 3, cc = (c & 7) << 3;
      *(uint4*)&Vs[r * 72 + cc] = *(const uint4*)&Vp[(long)r * T_ + cc];
    }
    __syncthreads();

    // S = Q K^T (each wave: its 16 Q rows x 64 s cols)
    f32x4 sacc[4] = {};
    #pragma unroll
    for (int kb = 0; kb < 4; ++kb) {
      const bf16x8 aq = *(const bf16x8*)&Qs[(wave * 16 + l16) * 136 + kb * 32 + quad * 8];
      #pragma unroll
      for (int nb = 0; nb < 4; ++nb) {
        const bf16x8 bk = *(const bf16x8*)&Ks[(nb * 16 + l16) * 136 + kb * 32 + quad * 8];
        sacc[nb] = __builtin_amdgcn_mfma_f32_16x16x32_bf16(aq, bk, sacc[nb], 0, 0, 0);
      }
    }

    // mask + online softmax (rows live at quad*4+r, cols at l16)
    float sv[4][4];
    float rmax[4] = {-INFINITY, -INFINITY, -INFINITY, -INFINITY};
    const int colb = s0 + l16;
    const int rowb = t0 + wave * 16 + quad * 4;
    #pragma unroll
    for (int nb = 0; nb < 4; ++nb)
      #pragma unroll
      for (int r = 0; r < 4; ++r) {
        float v = sacc[nb][r] * 0.08838834764831845f;  // HD^-0.5
        const int s = colb + nb * 16, tq = rowb + r;
        if (s > tq || s < tq - (WIN_ - 1)) v = -INFINITY;
        sv[nb][r] = v;
        rmax[r] = fmaxf(rmax[r], v);
      }
    #pragma unroll
    for (int r = 0; r < 4; ++r)
      #pragma unroll
      for (int off = 1; off < 16; off <<= 1)
        rmax[r] = fmaxf(rmax[r], __shfl_xor(rmax[r], off, 64));
    float alpha[4], rsum[4];
    #pragma unroll
    for (int r = 0; r < 4; ++r) {
      const float mn = fmaxf(m_i[r], rmax[r]);
      alpha[r] = __expf(m_i[r] - mn);
      m_i[r] = mn;
      rsum[r] = 0.0f;
    }
    #pragma unroll
    for (int nb = 0; nb < 4; ++nb)
      #pragma unroll
      for (int r = 0; r < 4; ++r) {
        const float p = __expf(sv[nb][r] - m_i[r]);   // masked -> exp(-inf)=0
        rsum[r] += p;
        Ps[(wave * 16 + quad * 4 + r) * 72 + nb * 16 + l16] = f2b(p);
      }
    #pragma unroll
    for (int r = 0; r < 4; ++r) {
      #pragma unroll
      for (int off = 1; off < 16; off <<= 1)
        rsum[r] += __shfl_xor(rsum[r], off, 64);
      l_i[r] = l_i[r] * alpha[r] + rsum[r];
    }
    #pragma unroll
    for (int nb = 0; nb < 8; ++nb)
      #pragma unroll
      for (int r = 0; r < 4; ++r)
        Oacc[nb][r] *= alpha[r];
    __syncthreads();  // P visible before A-layout re-read

    // O += P V  (A = P rows of this wave, B = V^T tile)
    #pragma unroll
    for (int ks = 0; ks < 2; ++ks) {
      const bf16x8 ap = *(const bf16x8*)&Ps[(wave * 16 + l16) * 72 + ks * 32 + quad * 8];
      #pragma unroll
      for (int nb = 0; nb < 8; ++nb) {
        const bf16x8 bv = *(const bf16x8*)&Vs[(nb * 16 + l16) * 72 + ks * 32 + quad * 8];
        Oacc[nb] = __builtin_amdgcn_mfma_f32_16x16x32_bf16(ap, bv, Oacc[nb], 0, 0, 0);
      }
    }
  }

  float rcp[4];
  #pragma unroll
  for (int r = 0; r < 4; ++r) rcp[r] = 1.0f / l_i[r];
  bf16* outp = attnb + ((long)(b * T_ + t0 + wave * 16 + quad * 4)) * EMB_ + h * HD_ + l16;
  #pragma unroll
  for (int nb = 0; nb < 8; ++nb)
    #pragma unroll
    for (int r = 0; r < 4; ++r)
      outp[(long)r * EMB_ + nb * 16] = f2b(Oacc[nb][r] * rcp[r]);
}

extern "C" void kernel_launch(void* const* d_in, const int* in_sizes, int n_in,
                              void* d_out, int out_size, void* d_ws, size_t ws_size,
                              hipStream_t stream)
{
  (void)in_sizes; (void)n_in; (void)out_size; (void)ws_size;
  const float* x    = (const float*)d_in[0];
  const float* wq   = (const float*)d_in[2];
  const float* wk   = (const float*)d_in[3];
  const float* wv   = (const float*)d_in[4];
  const float* wo   = (const float*)d_in[5];
  const float* sink = (const float*)d_in[6];
  const float* gw   = (const float*)d_in[7];
  const float* uw   = (const float*)d_in[8];
  const float* dw   = (const float*)d_in[9];
  const float* n1   = (const float*)d_in[10];
  const float* n2   = (const float*)d_in[11];

  // ---- workspace: 184.5 MB total via phase aliasing ----
  // R0 hbuf 16.78M | R1 67.11M (phaseA: qkv/Q/K/VT + attnb aliases qkv;
  // phaseB: gbuf) | R2 33.55M (phaseA: wqkvT+woT; phaseB: gateT->upT->downT)
  // | R3 mact 67.11M.  x1 (attn residual, f32) lives in d_out.
  char* base = (char*)d_ws;
  bf16*  hbuf  = (bf16*)base;                                   // 16,777,216
  char*  R1    = base + (size_t)16777216;                       // 67,108,864
  char*  R2    = R1   + (size_t)67108864;                       // 33,554,432
  bf16*  mact  = (bf16*)(R2 + (size_t)33554432);                // 67,108,864

  // phase A views
  bf16* qkv   = (bf16*)R1;                                      // 25,165,824
  bf16* Qb    = (bf16*)(R1 + 25165824);                         // 16,777,216
  bf16* Kb    = (bf16*)(R1 + 41943040);                         //  4,194,304
  bf16* VTb   = (bf16*)(R1 + 46137344);                         //  4,194,304
  bf16* attnb = (bf16*)R1;            // aliases qkv (dead after rope)
  bf16* wqkvT = (bf16*)R2;                                      // 12,582,912
  bf16* woT   = (bf16*)(R2 + 12582912);                         //  8,388,608
  // phase B views
  bf16* gbuf  = (bf16*)R1;            // 67,108,864
  bf16* wT    = (bf16*)R2;            // gateT / upT / downT, 33,554,432 each
  float* x1   = (float*)d_out;        // residual after attention

  const dim3 tb(32, 8);
  // ---- phase A: attention ----
  transpose_kernel<<<dim3( 64,  64), tb, 0, stream>>>(wq, wqkvT,                      EMB_, EMB_);
  transpose_kernel<<<dim3( 16,  64), tb, 0, stream>>>(wk, wqkvT + (size_t)2048*EMB_,  EMB_, 512);
  transpose_kernel<<<dim3( 16,  64), tb, 0, stream>>>(wv, wqkvT + (size_t)2560*EMB_,  EMB_, 512);
  transpose_kernel<<<dim3( 64,  64), tb, 0, stream>>>(wo, woT,                        EMB_, EMB_);

  rmsnorm_kernel<<<BT_, 256, 0, stream>>>(x, n1, hbuf);
  gemm_kernel<0><<<dim3(QKVN_/128, BT_/128), 256, 0, stream>>>(hbuf, wqkvT, qkv, nullptr, nullptr, BT_, QKVN_, EMB_);
  rope_kernel<<<dim3(T_, B_), 256, 0, stream>>>(qkv, Qb, Kb, VTb);
  attn_kernel<<<dim3(T_/64, B_*NH_), 256, 0, stream>>>(Qb, Kb, VTb, sink, attnb);
  gemm_kernel<1><<<dim3(EMB_/128, BT_/128), 256, 0, stream>>>(attnb, woT, x1, x, nullptr, BT_, EMB_, EMB_);

  // ---- phase B: MLP (R2 reused per-weight just-in-time; stream-ordered) ----
  rmsnorm_kernel<<<BT_, 256, 0, stream>>>(x1, n2, hbuf);
  transpose_kernel<<<dim3(256,  64), tb, 0, stream>>>(gw, wT, EMB_, MLPD_);
  gemm_kernel<0><<<dim3(MLPD_/128, BT_/128), 256, 0, stream>>>(hbuf, wT, gbuf, nullptr, nullptr, BT_, MLPD_, EMB_);
  transpose_kernel<<<dim3(256,  64), tb, 0, stream>>>(uw, wT, EMB_, MLPD_);
  gemm_kernel<2><<<dim3(MLPD_/128, BT_/128), 256, 0, stream>>>(hbuf, wT, mact, nullptr, gbuf, BT_, MLPD_, EMB_);
  transpose_kernel<<<dim3( 64, 256), tb, 0, stream>>>(dw, wT, MLPD_, EMB_);
  gemm_kernel<1><<<dim3(EMB_/128, BT_/128), 256, 0, stream>>>(mact, wT, (float*)d_out, x1, nullptr, BT_, EMB_, MLPD_);
}

// Round 3
// 1114.023 us; speedup vs baseline: 1.0508x; 1.0508x over previous
//
#include <hip/hip_runtime.h>
#include <hip/hip_bf16.h>
#include <stdint.h>

#define B_    2
#define T_    2048
#define EMB_  2048
#define NH_   16
#define NKV_  4
#define HD_   128
#define MLPD_ 8192
#define WIN_  1024
#define BT_   (B_ * T_)     // 4096 rows
#define QKVN_ 3072          // NH*HD + NKV*HD + NKV*HD

typedef __bf16 bf16;
typedef __bf16 bf16x8 __attribute__((ext_vector_type(8)));
typedef float  f32x4  __attribute__((ext_vector_type(4)));

__device__ __forceinline__ bf16 f2b(float f) {
  __hip_bfloat16 h = __float2bfloat16(f);
  return *reinterpret_cast<bf16*>(&h);
}
__device__ __forceinline__ float b2f(bf16 b) {
  __hip_bfloat16 h = *reinterpret_cast<__hip_bfloat16*>(&b);
  return __bfloat162float(h);
}

__device__ __forceinline__ void load_lds16(const void* g, void* l) {
  __builtin_amdgcn_global_load_lds(
      (const __attribute__((address_space(1))) void*)g,
      (__attribute__((address_space(3))) void*)l, 16, 0, 0);
}

// grouped swizzle: 8 consecutive linear blocks share one N-tile across XCDs.
// requires gridM (blockDim.y extent) divisible by 8 — true for all our GEMMs.
__device__ __forceinline__ void swz(int& mt, int& nt) {
  const int gridN = gridDim.x;
  const int lin = blockIdx.y * gridN + blockIdx.x;
  const int per = 8 * gridN;
  const int grp = lin / per, rem = lin % per;
  mt = (grp << 3) + (rem & 7);
  nt = rem >> 3;
}

// ---------- transpose f32 [R][C] -> bf16 [C][R] ----------
__global__ __launch_bounds__(256) void transpose_kernel(
    const float* __restrict__ in, bf16* __restrict__ out, int R, int C)
{
  __shared__ float tile[32][33];
  const int tx = threadIdx.x, ty = threadIdx.y;  // blockDim (32,8)
  const int c0 = blockIdx.x * 32, r0 = blockIdx.y * 32;
  #pragma unroll
  for (int i = 0; i < 32; i += 8)
    tile[ty + i][tx] = in[(long)(r0 + ty + i) * C + c0 + tx];
  __syncthreads();
  #pragma unroll
  for (int i = 0; i < 32; i += 8)
    out[(long)(c0 + ty + i) * R + r0 + tx] = f2b(tile[tx][ty + i]);
}

// ---------- RMSNorm: f32 row -> bf16 row ----------
__global__ __launch_bounds__(256) void rmsnorm_kernel(
    const float* __restrict__ x, const float* __restrict__ scale,
    bf16* __restrict__ out)
{
  const long row = blockIdx.x;
  const float* xr = x + row * EMB_;
  bf16* orow = out + row * EMB_;
  const float4 v0 = ((const float4*)xr)[threadIdx.x];
  const float4 v1 = ((const float4*)xr)[threadIdx.x + 256];
  float ss = v0.x*v0.x + v0.y*v0.y + v0.z*v0.z + v0.w*v0.w
           + v1.x*v1.x + v1.y*v1.y + v1.z*v1.z + v1.w*v1.w;
  #pragma unroll
  for (int off = 32; off >= 1; off >>= 1) ss += __shfl_xor(ss, off, 64);
  __shared__ float red[4];
  if ((threadIdx.x & 63) == 0) red[threadIdx.x >> 6] = ss;
  __syncthreads();
  const float tot = red[0] + red[1] + red[2] + red[3];
  const float rs = rsqrtf(tot * (1.0f / EMB_) + 1e-6f);
  const float4 s0 = ((const float4*)scale)[threadIdx.x];
  const float4 s1 = ((const float4*)scale)[threadIdx.x + 256];
  const int c0 = threadIdx.x * 4;
  orow[c0 + 0]    = f2b(v0.x * rs * (1.0f + s0.x));
  orow[c0 + 1]    = f2b(v0.y * rs * (1.0f + s0.y));
  orow[c0 + 2]    = f2b(v0.z * rs * (1.0f + s0.z));
  orow[c0 + 3]    = f2b(v0.w * rs * (1.0f + s0.w));
  orow[c0 + 1024] = f2b(v1.x * rs * (1.0f + s1.x));
  orow[c0 + 1025] = f2b(v1.y * rs * (1.0f + s1.y));
  orow[c0 + 1026] = f2b(v1.z * rs * (1.0f + s1.z));
  orow[c0 + 1027] = f2b(v1.w * rs * (1.0f + s1.w));
}

// ---------- GEMM: C[M][N] = A[M][K] * Bt[N][K]^T, bf16 in, f32 acc ----------
// EPI 0: bf16 out.  EPI 1: f32 out = acc + res (res may alias out, same-elem RMW).
template <int EPI>
__global__ __launch_bounds__(256) void gemm_kernel(
    const bf16* __restrict__ A, const bf16* __restrict__ Bt,
    void* __restrict__ out, const float* __restrict__ res,
    int M, int N, int K)
{
  __shared__ __align__(16) bf16 As[128 * 32];
  __shared__ __align__(16) bf16 Bs[128 * 32];
  const int tid  = threadIdx.x;
  const int wave = tid >> 6, lane = tid & 63;
  int mt, nt; swz(mt, nt);
  const int bm = mt << 7, bn = nt << 7;
  const int wm = (wave & 1) << 6, wn = (wave >> 1) << 6;
  const int l16 = lane & 15, quad = lane >> 4;
  const int srow = lane >> 2, scol = (lane & 3) << 3;

  const bf16* Ap = A  + (long)(bm + wave * 32 + srow) * K + scol;
  const bf16* Bp = Bt + (long)(bn + wave * 32 + srow) * K + scol;
  char* ldsA = (char*)As + wave * 2048;
  char* ldsB = (char*)Bs + wave * 2048;

  f32x4 acc[4][4] = {};

  for (int k0 = 0; k0 < K; k0 += 32) {
    __syncthreads();
    #pragma unroll
    for (int j = 0; j < 2; ++j) {
      load_lds16(Ap + (long)j * 16 * K + k0, ldsA + j * 1024);
      load_lds16(Bp + (long)j * 16 * K + k0, ldsB + j * 1024);
    }
    __syncthreads();
    bf16x8 af[4], bfr[4];
    #pragma unroll
    for (int i = 0; i < 4; ++i) {
      af[i]  = *(const bf16x8*)&As[(wm + i * 16 + l16) * 32 + quad * 8];
      bfr[i] = *(const bf16x8*)&Bs[(wn + i * 16 + l16) * 32 + quad * 8];
    }
    #pragma unroll
    for (int mb = 0; mb < 4; ++mb)
      #pragma unroll
      for (int nb = 0; nb < 4; ++nb)
        acc[mb][nb] = __builtin_amdgcn_mfma_f32_16x16x32_bf16(af[mb], bfr[nb], acc[mb][nb], 0, 0, 0);
  }

  const int crow = bm + wm + (quad << 2);
  const int ccol = bn + wn + l16;
  #pragma unroll
  for (int mb = 0; mb < 4; ++mb)
    #pragma unroll
    for (int nb = 0; nb < 4; ++nb)
      #pragma unroll
      for (int r = 0; r < 4; ++r) {
        const long idx = (long)(crow + mb * 16 + r) * N + (ccol + nb * 16);
        const float v = acc[mb][nb][r];
        if (EPI == 0) {
          ((bf16*)out)[idx] = f2b(v);
        } else {
          ((float*)out)[idx] = v + res[idx];
        }
      }
}

// ---------- Fused gate+up MLP GEMM: out = silu(A*Bg^T) * (A*Bu^T), bf16 ----------
// 512 threads = 8 waves. Waves 0-3: gate tile; waves 4-7: up tile. Shared A stage.
// LDS: staging A(8K)+Bg(8K)+Bu(8K)=24K; epilogue exchange overlays 32K. Total 32K.
__global__ __launch_bounds__(512) void mlp_gateup_kernel(
    const bf16* __restrict__ A, const bf16* __restrict__ Bg,
    const bf16* __restrict__ Bu, bf16* __restrict__ out,
    int M, int N, int K)
{
  __shared__ __align__(16) char smem[32768];
  const int tid = threadIdx.x;
  const int wave = tid >> 6, lane = tid & 63;
  const int role = wave >> 2, wq = wave & 3;
  const int wm = (wq & 1) << 6, wn = (wq >> 1) << 6;
  const int l16 = lane & 15, quad = lane >> 4;
  const int srow = lane >> 2, scol = (lane & 3) << 3;

  int mt, nt; swz(mt, nt);
  const int bm = mt << 7, bn = nt << 7;

  // 24 staging chunks of 16 rows x 32 cols (1 KB each): 3 per wave.
  const bf16* sp[3]; char* dp[3];
  #pragma unroll
  for (int j = 0; j < 3; ++j) {
    const int c = 3 * wave + j;
    const int buf = c >> 3, r0 = (c & 7) << 4;
    const bf16* gbase = (buf == 0) ? A + (long)bm * K
                      : (buf == 1) ? Bg + (long)bn * K
                                   : Bu + (long)bn * K;
    sp[j] = gbase + (long)(r0 + srow) * K + scol;   // per-lane global src
    dp[j] = smem + buf * 8192 + (c & 7) * 1024;     // wave-uniform LDS dst
  }
  const bf16* Asb = (const bf16*)smem;
  const bf16* Bsb = (const bf16*)(smem + 8192 + role * 8192);

  f32x4 acc[4][4] = {};

  for (int k0 = 0; k0 < K; k0 += 32) {
    __syncthreads();
    #pragma unroll
    for (int j = 0; j < 3; ++j) load_lds16(sp[j] + k0, dp[j]);
    __syncthreads();
    bf16x8 af[4], bfr[4];
    #pragma unroll
    for (int i = 0; i < 4; ++i) {
      af[i]  = *(const bf16x8*)&Asb[(wm + i * 16 + l16) * 32 + quad * 8];
      bfr[i] = *(const bf16x8*)&Bsb[(wn + i * 16 + l16) * 32 + quad * 8];
    }
    #pragma unroll
    for (int mb = 0; mb < 4; ++mb)
      #pragma unroll
      for (int nb = 0; nb < 4; ++nb)
        acc[mb][nb] = __builtin_amdgcn_mfma_f32_16x16x32_bf16(af[mb], bfr[nb], acc[mb][nb], 0, 0, 0);
  }

  __syncthreads();                    // staging LDS dead; Ex overlays it
  bf16* Ex = (bf16*)smem;             // 128x128 bf16 = 32 KB
  const int rw = wm + (quad << 2), cw = wn + l16;
  if (role == 0) {
    #pragma unroll
    for (int mb = 0; mb < 4; ++mb)
      #pragma unroll
      for (int nb = 0; nb < 4; ++nb)
        #pragma unroll
        for (int r = 0; r < 4; ++r) {
          const float g = acc[mb][nb][r];
          Ex[(rw + mb * 16 + r) * 128 + cw + nb * 16] = f2b(g / (1.0f + __expf(-g)));
        }
  }
  __syncthreads();
  if (role == 1) {
    #pragma unroll
    for (int mb = 0; mb < 4; ++mb)
      #pragma unroll
      for (int nb = 0; nb < 4; ++nb)
        #pragma unroll
        for (int r = 0; r < 4; ++r) {
          const float sg = b2f(Ex[(rw + mb * 16 + r) * 128 + cw + nb * 16]);
          out[(long)(bm + rw + mb * 16 + r) * N + bn + cw + nb * 16] =
              f2b(acc[mb][nb][r] * sg);
        }
  }
}

// ---------- RoPE + layout: qkv bf16 [BT][3072] -> Q [B][NH][T][HD],
//            K [B][NKV][T][HD], V^T [B][NKV][HD][T] ----------
__global__ __launch_bounds__(256) void rope_kernel(
    const bf16* __restrict__ qkv, bf16* __restrict__ Q,
    bf16* __restrict__ K, bf16* __restrict__ VT)
{
  const int t = blockIdx.x, b = blockIdx.y;
  const bf16* row = qkv + (long)(b * T_ + t) * QKVN_;
  const float tf = (float)t;  // positions = t (segment_ids all-ones, cur_ind=0)
  for (int idx = threadIdx.x; idx < NH_ * HD_; idx += 256) {
    const int head = idx >> 7, hd = idx & 127;
    const float v = b2f(row[idx]);
    float o;
    if (hd < 64) {
      const int j = hd & 31;
      const float ang = tf * expf(-(float)j * 0.28782313662425574f); // ln(1e4)/32
      const float sn = sinf(ang), cs = cosf(ang);
      o = (hd < 32) ? (v * cs - b2f(row[idx + 32]) * sn)
                    : (v * cs + b2f(row[idx - 32]) * sn);
    } else o = v;
    Q[((long)(b * NH_ + head) * T_ + t) * HD_ + hd] = f2b(o);
  }
  for (int idx = threadIdx.x; idx < NKV_ * HD_; idx += 256) {
    const int kv = idx >> 7, hd = idx & 127;
    const float v = b2f(row[NH_ * HD_ + idx]);
    float o;
    if (hd < 64) {
      const int j = hd & 31;
      const float ang = tf * expf(-(float)j * 0.28782313662425574f);
      const float sn = sinf(ang), cs = cosf(ang);
      o = (hd < 32) ? (v * cs - b2f(row[NH_ * HD_ + idx + 32]) * sn)
                    : (v * cs + b2f(row[NH_ * HD_ + idx - 32]) * sn);
    } else o = v;
    K[((long)(b * NKV_ + kv) * T_ + t) * HD_ + hd] = f2b(o);
  }
  for (int idx = threadIdx.x; idx < NKV_ * HD_; idx += 256) {
    const int kv = idx >> 7, vd = idx & 127;
    VT[((long)(b * NKV_ + kv) * HD_ + vd) * T_ + t] = row[(NH_ + NKV_) * HD_ + idx];
  }
}

// ---------- Flash attention: 64-row Q tile per block, window 1024, sink ----------
__global__ __launch_bounds__(256) void attn_kernel(
    const bf16* __restrict__ Q, const bf16* __restrict__ Kg,
    const bf16* __restrict__ VTg, const float* __restrict__ sink,
    bf16* __restrict__ attnb)
{
  __shared__ __align__(16) bf16 Qs[64 * 136];   // padded: stride 136 elems (272B)
  __shared__ __align__(16) bf16 Ks[64 * 136];
  __shared__ __align__(16) bf16 Vs[128 * 72];   // V^T tile, stride 72 (144B)
  __shared__ __align__(16) bf16 Ps[64 * 72];    // P round-trip C-layout -> A-layout

  const int qt = blockIdx.x;
  const int bh = blockIdx.y;
  const int b = bh >> 4, h = bh & 15;
  const int kvh = h >> 2;            // GQA: 4 q-heads per kv-head
  const int t0 = qt * 64;
  const int tid = threadIdx.x;
  const int wave = tid >> 6, lane = tid & 63;
  const int quad = lane >> 4, l16 = lane & 15;

  const bf16* Qp = Q + ((long)(b * NH_ + h) * T_ + t0) * HD_;
  #pragma unroll
  for (int c = tid; c < 1024; c += 256) {
    const int r = c >> 4, cc = (c & 15) << 3;
    *(uint4*)&Qs[r * 136 + cc] = *(const uint4*)&Qp[r * HD_ + cc];
  }

  float m_i[4], l_i[4];
  const float sb = sink[h];
  #pragma unroll
  for (int r = 0; r < 4; ++r) { m_i[r] = sb; l_i[r] = 1.0f; }  // sink column
  f32x4 Oacc[8] = {};

  const int st_lo = (qt > 16) ? (qt - 16) : 0;
  for (int st = st_lo; st <= qt; ++st) {
    const int s0 = st * 64;
    __syncthreads();
    const bf16* Kp = Kg + ((long)(b * NKV_ + kvh) * T_ + s0) * HD_;
    #pragma unroll
    for (int c = tid; c < 1024; c += 256) {
      const int r = c >> 4, cc = (c & 15) << 3;
      *(uint4*)&Ks[r * 136 + cc] = *(const uint4*)&Kp[r * HD_ + cc];
    }
    const bf16* Vp = VTg + (long)(b * NKV_ + kvh) * HD_ * T_ + s0;
    #pragma unroll
    for (int c = tid; c < 1024; c += 256) {
      const int r = c >> 3, cc = (c & 7) << 3;
      *(uint4*)&Vs[r * 72 + cc] = *(const uint4*)&Vp[(long)r * T_ + cc];
    }
    __syncthreads();

    // S = Q K^T (each wave: its 16 Q rows x 64 s cols)
    f32x4 sacc[4] = {};
    #pragma unroll
    for (int kb = 0; kb < 4; ++kb) {
      const bf16x8 aq = *(const bf16x8*)&Qs[(wave * 16 + l16) * 136 + kb * 32 + quad * 8];
      #pragma unroll
      for (int nb = 0; nb < 4; ++nb) {
        const bf16x8 bk = *(const bf16x8*)&Ks[(nb * 16 + l16) * 136 + kb * 32 + quad * 8];
        sacc[nb] = __builtin_amdgcn_mfma_f32_16x16x32_bf16(aq, bk, sacc[nb], 0, 0, 0);
      }
    }

    // mask + online softmax (rows live at quad*4+r, cols at l16)
    float sv[4][4];
    float rmax[4] = {-INFINITY, -INFINITY, -INFINITY, -INFINITY};
    const int colb = s0 + l16;
    const int rowb = t0 + wave * 16 + quad * 4;
    #pragma unroll
    for (int nb = 0; nb < 4; ++nb)
      #pragma unroll
      for (int r = 0; r < 4; ++r) {
        float v = sacc[nb][r] * 0.08838834764831845f;  // HD^-0.5
        const int s = colb + nb * 16, tq = rowb + r;
        if (s > tq || s < tq - (WIN_ - 1)) v = -INFINITY;
        sv[nb][r] = v;
        rmax[r] = fmaxf(rmax[r], v);
      }
    #pragma unroll
    for (int r = 0; r < 4; ++r)
      #pragma unroll
      for (int off = 1; off < 16; off <<= 1)
        rmax[r] = fmaxf(rmax[r], __shfl_xor(rmax[r], off, 64));
    float alpha[4], rsum[4];
    #pragma unroll
    for (int r = 0; r < 4; ++r) {
      const float mn = fmaxf(m_i[r], rmax[r]);
      alpha[r] = __expf(m_i[r] - mn);
      m_i[r] = mn;
      rsum[r] = 0.0f;
    }
    #pragma unroll
    for (int nb = 0; nb < 4; ++nb)
      #pragma unroll
      for (int r = 0; r < 4; ++r) {
        const float p = __expf(sv[nb][r] - m_i[r]);   // masked -> exp(-inf)=0
        rsum[r] += p;
        Ps[(wave * 16 + quad * 4 + r) * 72 + nb * 16 + l16] = f2b(p);
      }
    #pragma unroll
    for (int r = 0; r < 4; ++r) {
      #pragma unroll
      for (int off = 1; off < 16; off <<= 1)
        rsum[r] += __shfl_xor(rsum[r], off, 64);
      l_i[r] = l_i[r] * alpha[r] + rsum[r];
    }
    #pragma unroll
    for (int nb = 0; nb < 8; ++nb)
      #pragma unroll
      for (int r = 0; r < 4; ++r)
        Oacc[nb][r] *= alpha[r];
    __syncthreads();  // P visible before A-layout re-read

    // O += P V  (A = P rows of this wave, B = V^T tile)
    #pragma unroll
    for (int ks = 0; ks < 2; ++ks) {
      const bf16x8 ap = *(const bf16x8*)&Ps[(wave * 16 + l16) * 72 + ks * 32 + quad * 8];
      #pragma unroll
      for (int nb = 0; nb < 8; ++nb) {
        const bf16x8 bv = *(const bf16x8*)&Vs[(nb * 16 + l16) * 72 + ks * 32 + quad * 8];
        Oacc[nb] = __builtin_amdgcn_mfma_f32_16x16x32_bf16(ap, bv, Oacc[nb], 0, 0, 0);
      }
    }
  }

  float rcp[4];
  #pragma unroll
  for (int r = 0; r < 4; ++r) rcp[r] = 1.0f / l_i[r];
  bf16* outp = attnb + ((long)(b * T_ + t0 + wave * 16 + quad * 4)) * EMB_ + h * HD_ + l16;
  #pragma unroll
  for (int nb = 0; nb < 8; ++nb)
    #pragma unroll
    for (int r = 0; r < 4; ++r)
      outp[(long)r * EMB_ + nb * 16] = f2b(Oacc[nb][r] * rcp[r]);
}

extern "C" void kernel_launch(void* const* d_in, const int* in_sizes, int n_in,
                              void* d_out, int out_size, void* d_ws, size_t ws_size,
                              hipStream_t stream)
{
  (void)in_sizes; (void)n_in; (void)out_size; (void)ws_size;
  const float* x    = (const float*)d_in[0];
  const float* wq   = (const float*)d_in[2];
  const float* wk   = (const float*)d_in[3];
  const float* wv   = (const float*)d_in[4];
  const float* wo   = (const float*)d_in[5];
  const float* sink = (const float*)d_in[6];
  const float* gw   = (const float*)d_in[7];
  const float* uw   = (const float*)d_in[8];
  const float* dw   = (const float*)d_in[9];
  const float* n1   = (const float*)d_in[10];
  const float* n2   = (const float*)d_in[11];

  // ---- workspace: 184.5 MB via phase aliasing ----
  // R0 hbuf 16.78M | R1 67.11M (phaseA: qkv/Q/K/VT, attnb aliases qkv;
  // phaseB: gateT+upT) | R2 33.55M (phaseA: wqkvT+woT; phaseB: downT)
  // | R3 mact 67.11M.  x1 (attn residual, f32) lives in d_out.
  char* base = (char*)d_ws;
  bf16*  hbuf  = (bf16*)base;                                   // 16,777,216
  char*  R1    = base + (size_t)16777216;                       // 67,108,864
  char*  R2    = R1   + (size_t)67108864;                       // 33,554,432
  bf16*  mact  = (bf16*)(R2 + (size_t)33554432);                // 67,108,864

  // phase A views
  bf16* qkv   = (bf16*)R1;                                      // 25,165,824
  bf16* Qb    = (bf16*)(R1 + 25165824);                         // 16,777,216
  bf16* Kb    = (bf16*)(R1 + 41943040);                         //  4,194,304
  bf16* VTb   = (bf16*)(R1 + 46137344);                         //  4,194,304
  bf16* attnb = (bf16*)R1;            // aliases qkv (dead after rope)
  bf16* wqkvT = (bf16*)R2;                                      // 12,582,912
  bf16* woT   = (bf16*)(R2 + 12582912);                         //  8,388,608
  // phase B views
  bf16* gateT = (bf16*)R1;                                      // 33,554,432
  bf16* upT   = (bf16*)(R1 + 33554432);                         // 33,554,432
  bf16* downT = (bf16*)R2;                                      // 33,554,432
  float* x1   = (float*)d_out;        // residual after attention

  const dim3 tb(32, 8);
  // ---- phase A: attention ----
  transpose_kernel<<<dim3( 64,  64), tb, 0, stream>>>(wq, wqkvT,                      EMB_, EMB_);
  transpose_kernel<<<dim3( 16,  64), tb, 0, stream>>>(wk, wqkvT + (size_t)2048*EMB_,  EMB_, 512);
  transpose_kernel<<<dim3( 16,  64), tb, 0, stream>>>(wv, wqkvT + (size_t)2560*EMB_,  EMB_, 512);
  transpose_kernel<<<dim3( 64,  64), tb, 0, stream>>>(wo, woT,                        EMB_, EMB_);

  rmsnorm_kernel<<<BT_, 256, 0, stream>>>(x, n1, hbuf);
  gemm_kernel<0><<<dim3(QKVN_/128, BT_/128), 256, 0, stream>>>(hbuf, wqkvT, qkv, nullptr, BT_, QKVN_, EMB_);
  rope_kernel<<<dim3(T_, B_), 256, 0, stream>>>(qkv, Qb, Kb, VTb);
  attn_kernel<<<dim3(T_/64, B_*NH_), 256, 0, stream>>>(Qb, Kb, VTb, sink, attnb);
  gemm_kernel<1><<<dim3(EMB_/128, BT_/128), 256, 0, stream>>>(attnb, woT, x1, x, BT_, EMB_, EMB_);

  // ---- phase B: MLP ----
  rmsnorm_kernel<<<BT_, 256, 0, stream>>>(x1, n2, hbuf);
  transpose_kernel<<<dim3(256,  64), tb, 0, stream>>>(gw, gateT, EMB_, MLPD_);
  transpose_kernel<<<dim3(256,  64), tb, 0, stream>>>(uw, upT,   EMB_, MLPD_);
  mlp_gateup_kernel<<<dim3(MLPD_/128, BT_/128), 512, 0, stream>>>(hbuf, gateT, upT, mact, BT_, MLPD_, EMB_);
  transpose_kernel<<<dim3( 64, 256), tb, 0, stream>>>(dw, downT, MLPD_, EMB_);
  gemm_kernel<1><<<dim3(EMB_/128, BT_/128), 256, 0, stream>>>(mact, downT, (float*)d_out, x1, BT_, EMB_, MLPD_);
}

// Round 4
// 1103.539 us; speedup vs baseline: 1.0608x; 1.0095x over previous
//
#include <hip/hip_runtime.h>
#include <hip/hip_bf16.h>
#include <stdint.h>

#define B_    2
#define T_    2048
#define EMB_  2048
#define NH_   16
#define NKV_  4
#define HD_   128
#define MLPD_ 8192
#define WIN_  1024
#define BT_   (B_ * T_)     // 4096 rows
#define QKVN_ 3072          // NH*HD + NKV*HD + NKV*HD

typedef __bf16 bf16;
typedef __bf16 bf16x8 __attribute__((ext_vector_type(8)));
typedef float  f32x4  __attribute__((ext_vector_type(4)));

__device__ __forceinline__ bf16 f2b(float f) {
  __hip_bfloat16 h = __float2bfloat16(f);
  return *reinterpret_cast<bf16*>(&h);
}
__device__ __forceinline__ float b2f(bf16 b) {
  __hip_bfloat16 h = *reinterpret_cast<__hip_bfloat16*>(&b);
  return __bfloat162float(h);
}

__device__ __forceinline__ void load_lds16(const void* g, void* l) {
  __builtin_amdgcn_global_load_lds(
      (const __attribute__((address_space(1))) void*)g,
      (__attribute__((address_space(3))) void*)l, 16, 0, 0);
}

// ---------- transpose f32 [R][C] -> bf16 [C][R] ----------
__global__ __launch_bounds__(256) void transpose_kernel(
    const float* __restrict__ in, bf16* __restrict__ out, int R, int C)
{
  __shared__ float tile[32][33];
  const int tx = threadIdx.x, ty = threadIdx.y;  // blockDim (32,8)
  const int c0 = blockIdx.x * 32, r0 = blockIdx.y * 32;
  #pragma unroll
  for (int i = 0; i < 32; i += 8)
    tile[ty + i][tx] = in[(long)(r0 + ty + i) * C + c0 + tx];
  __syncthreads();
  #pragma unroll
  for (int i = 0; i < 32; i += 8)
    out[(long)(c0 + ty + i) * R + r0 + tx] = f2b(tile[tx][ty + i]);
}

// ---------- RMSNorm: f32 row -> bf16 row ----------
__global__ __launch_bounds__(256) void rmsnorm_kernel(
    const float* __restrict__ x, const float* __restrict__ scale,
    bf16* __restrict__ out)
{
  const long row = blockIdx.x;
  const float* xr = x + row * EMB_;
  bf16* orow = out + row * EMB_;
  const float4 v0 = ((const float4*)xr)[threadIdx.x];
  const float4 v1 = ((const float4*)xr)[threadIdx.x + 256];
  float ss = v0.x*v0.x + v0.y*v0.y + v0.z*v0.z + v0.w*v0.w
           + v1.x*v1.x + v1.y*v1.y + v1.z*v1.z + v1.w*v1.w;
  #pragma unroll
  for (int off = 32; off >= 1; off >>= 1) ss += __shfl_xor(ss, off, 64);
  __shared__ float red[4];
  if ((threadIdx.x & 63) == 0) red[threadIdx.x >> 6] = ss;
  __syncthreads();
  const float tot = red[0] + red[1] + red[2] + red[3];
  const float rs = rsqrtf(tot * (1.0f / EMB_) + 1e-6f);
  const float4 s0 = ((const float4*)scale)[threadIdx.x];
  const float4 s1 = ((const float4*)scale)[threadIdx.x + 256];
  const int c0 = threadIdx.x * 4;
  orow[c0 + 0]    = f2b(v0.x * rs * (1.0f + s0.x));
  orow[c0 + 1]    = f2b(v0.y * rs * (1.0f + s0.y));
  orow[c0 + 2]    = f2b(v0.z * rs * (1.0f + s0.z));
  orow[c0 + 3]    = f2b(v0.w * rs * (1.0f + s0.w));
  orow[c0 + 1024] = f2b(v1.x * rs * (1.0f + s1.x));
  orow[c0 + 1025] = f2b(v1.y * rs * (1.0f + s1.y));
  orow[c0 + 1026] = f2b(v1.z * rs * (1.0f + s1.z));
  orow[c0 + 1027] = f2b(v1.w * rs * (1.0f + s1.w));
}

// ---------- GEMM: C[M][N] = A[M][K] * Bt[N][K]^T, bf16 in, f32 acc ----------
// EPI 0: bf16 out.  EPI 1: f32 out = acc + res (res may alias out, same-elem RMW).
template <int EPI>
__global__ __launch_bounds__(256) void gemm_kernel(
    const bf16* __restrict__ A, const bf16* __restrict__ Bt,
    void* __restrict__ out, const float* __restrict__ res,
    int M, int N, int K)
{
  __shared__ __align__(16) bf16 As[128 * 32];
  __shared__ __align__(16) bf16 Bs[128 * 32];
  const int tid  = threadIdx.x;
  const int wave = tid >> 6, lane = tid & 63;
  const int bm = blockIdx.y << 7, bn = blockIdx.x << 7;
  const int wm = (wave & 1) << 6, wn = (wave >> 1) << 6;
  const int l16 = lane & 15, quad = lane >> 4;
  const int srow = lane >> 2, scol = (lane & 3) << 3;

  const bf16* Ap = A  + (long)(bm + wave * 32 + srow) * K + scol;
  const bf16* Bp = Bt + (long)(bn + wave * 32 + srow) * K + scol;
  char* ldsA = (char*)As + wave * 2048;
  char* ldsB = (char*)Bs + wave * 2048;

  f32x4 acc[4][4] = {};

  for (int k0 = 0; k0 < K; k0 += 32) {
    __syncthreads();
    #pragma unroll
    for (int j = 0; j < 2; ++j) {
      load_lds16(Ap + (long)j * 16 * K + k0, ldsA + j * 1024);
      load_lds16(Bp + (long)j * 16 * K + k0, ldsB + j * 1024);
    }
    __syncthreads();
    bf16x8 af[4], bfr[4];
    #pragma unroll
    for (int i = 0; i < 4; ++i) {
      af[i]  = *(const bf16x8*)&As[(wm + i * 16 + l16) * 32 + quad * 8];
      bfr[i] = *(const bf16x8*)&Bs[(wn + i * 16 + l16) * 32 + quad * 8];
    }
    #pragma unroll
    for (int mb = 0; mb < 4; ++mb)
      #pragma unroll
      for (int nb = 0; nb < 4; ++nb)
        acc[mb][nb] = __builtin_amdgcn_mfma_f32_16x16x32_bf16(af[mb], bfr[nb], acc[mb][nb], 0, 0, 0);
  }

  const int crow = bm + wm + (quad << 2);
  const int ccol = bn + wn + l16;
  #pragma unroll
  for (int mb = 0; mb < 4; ++mb)
    #pragma unroll
    for (int nb = 0; nb < 4; ++nb)
      #pragma unroll
      for (int r = 0; r < 4; ++r) {
        const long idx = (long)(crow + mb * 16 + r) * N + (ccol + nb * 16);
        const float v = acc[mb][nb][r];
        if (EPI == 0) {
          ((bf16*)out)[idx] = f2b(v);
        } else {
          ((float*)out)[idx] = v + res[idx];
        }
      }
}

// ---------- Fused gate+up MLP GEMM: out = silu(A*Bg^T) * (A*Bu^T), bf16 ----------
// 512 threads = 8 waves. Waves 0-3: gate tile; waves 4-7: up tile. Shared A stage.
// BK=64 staged as two stacked BK=32 tiles (keeps load_lds contiguity + stride-64B
// conflict-free frag reads) -> barriers per K-loop halved vs BK=32.
// LDS: A 16K | Bg 16K | Bu 16K = 48K; epilogue Ex overlays first 32K.
__global__ __launch_bounds__(512) void mlp_gateup_kernel(
    const bf16* __restrict__ A, const bf16* __restrict__ Bg,
    const bf16* __restrict__ Bu, bf16* __restrict__ out,
    int M, int N, int K)
{
  __shared__ __align__(16) char smem[49152];
  const int tid = threadIdx.x;
  const int wave = tid >> 6, lane = tid & 63;
  const int role = wave >> 2, wq = wave & 3;
  const int wm = (wq & 1) << 6, wn = (wq >> 1) << 6;
  const int l16 = lane & 15, quad = lane >> 4;
  const int srow = lane >> 2, scol = (lane & 3) << 3;

  const int bm = blockIdx.y << 7, bn = blockIdx.x << 7;

  // 48 staging chunks of 16 rows x 32 cols (1 KB each): 6 per wave.
  // chunk c: buf = c>>4 (0=A,1=Bg,2=Bu); idx = c&15; kh = idx>>3 (k-half); r8 = idx&7.
  const bf16* sp[6]; char* dp[6];
  #pragma unroll
  for (int j = 0; j < 6; ++j) {
    const int c = 6 * wave + j;
    const int buf = c >> 4, idx = c & 15, kh = idx >> 3, r8 = idx & 7;
    const bf16* gbase = (buf == 0) ? A + (long)bm * K
                      : (buf == 1) ? Bg + (long)bn * K
                                   : Bu + (long)bn * K;
    sp[j] = gbase + (long)(r8 * 16 + srow) * K + kh * 32 + scol;  // per-lane src
    dp[j] = smem + buf * 16384 + kh * 8192 + r8 * 1024;           // wave-uniform dst
  }
  const bf16* Asb = (const bf16*)smem;
  const bf16* Bsb = (const bf16*)(smem + 16384 + role * 16384);

  f32x4 acc[4][4] = {};

  for (int k0 = 0; k0 < K; k0 += 64) {
    __syncthreads();
    #pragma unroll
    for (int j = 0; j < 6; ++j) load_lds16(sp[j] + k0, dp[j]);
    __syncthreads();
    #pragma unroll
    for (int kh = 0; kh < 2; ++kh) {
      bf16x8 af[4], bfr[4];
      #pragma unroll
      for (int i = 0; i < 4; ++i) {
        af[i]  = *(const bf16x8*)&Asb[kh * 4096 + (wm + i * 16 + l16) * 32 + quad * 8];
        bfr[i] = *(const bf16x8*)&Bsb[kh * 4096 + (wn + i * 16 + l16) * 32 + quad * 8];
      }
      #pragma unroll
      for (int mb = 0; mb < 4; ++mb)
        #pragma unroll
        for (int nb = 0; nb < 4; ++nb)
          acc[mb][nb] = __builtin_amdgcn_mfma_f32_16x16x32_bf16(af[mb], bfr[nb], acc[mb][nb], 0, 0, 0);
    }
  }

  __syncthreads();                    // staging LDS dead; Ex overlays it
  bf16* Ex = (bf16*)smem;             // 128x128 bf16 = 32 KB
  const int rw = wm + (quad << 2), cw = wn + l16;
  if (role == 0) {
    #pragma unroll
    for (int mb = 0; mb < 4; ++mb)
      #pragma unroll
      for (int nb = 0; nb < 4; ++nb)
        #pragma unroll
        for (int r = 0; r < 4; ++r) {
          const float g = acc[mb][nb][r];
          Ex[(rw + mb * 16 + r) * 128 + cw + nb * 16] = f2b(g / (1.0f + __expf(-g)));
        }
  }
  __syncthreads();
  if (role == 1) {
    #pragma unroll
    for (int mb = 0; mb < 4; ++mb)
      #pragma unroll
      for (int nb = 0; nb < 4; ++nb)
        #pragma unroll
        for (int r = 0; r < 4; ++r) {
          const float sg = b2f(Ex[(rw + mb * 16 + r) * 128 + cw + nb * 16]);
          out[(long)(bm + rw + mb * 16 + r) * N + bn + cw + nb * 16] =
              f2b(acc[mb][nb][r] * sg);
        }
  }
}

// ---------- Down-proj GEMM, shared-B: 512 thr, 256M x 128N tile ----------
// Waves 0-3: rows [bm, bm+128); waves 4-7: rows [bm+128, bm+256). Shared B stage.
// f32 out = acc + res (res may alias out; same-element RMW).
__global__ __launch_bounds__(512) void down_kernel(
    const bf16* __restrict__ A, const bf16* __restrict__ Bt,
    float* __restrict__ out, const float* __restrict__ res,
    int M, int N, int K)
{
  __shared__ __align__(16) char smem[24576];   // A0 8K | A1 8K | B 8K
  const int tid = threadIdx.x;
  const int wave = tid >> 6, lane = tid & 63;
  const int role = wave >> 2, wq = wave & 3;
  const int wm = (wq & 1) << 6, wn = (wq >> 1) << 6;
  const int l16 = lane & 15, quad = lane >> 4;
  const int srow = lane >> 2, scol = (lane & 3) << 3;

  const int bm = blockIdx.y << 8, bn = blockIdx.x << 7;

  // 24 staging chunks of 16 rows x 32 cols: 3 per wave.
  const bf16* sp[3]; char* dp[3];
  #pragma unroll
  for (int j = 0; j < 3; ++j) {
    const int c = 3 * wave + j;
    const int buf = c >> 3, r0 = (c & 7) << 4;
    const bf16* gbase = (buf == 0) ? A + (long)bm * K
                      : (buf == 1) ? A + (long)(bm + 128) * K
                                   : Bt + (long)bn * K;
    sp[j] = gbase + (long)(r0 + srow) * K + scol;
    dp[j] = smem + buf * 8192 + (c & 7) * 1024;
  }
  const bf16* Asb = (const bf16*)(smem + role * 8192);
  const bf16* Bsb = (const bf16*)(smem + 16384);

  f32x4 acc[4][4] = {};

  for (int k0 = 0; k0 < K; k0 += 32) {
    __syncthreads();
    #pragma unroll
    for (int j = 0; j < 3; ++j) load_lds16(sp[j] + k0, dp[j]);
    __syncthreads();
    bf16x8 af[4], bfr[4];
    #pragma unroll
    for (int i = 0; i < 4; ++i) {
      af[i]  = *(const bf16x8*)&Asb[(wm + i * 16 + l16) * 32 + quad * 8];
      bfr[i] = *(const bf16x8*)&Bsb[(wn + i * 16 + l16) * 32 + quad * 8];
    }
    #pragma unroll
    for (int mb = 0; mb < 4; ++mb)
      #pragma unroll
      for (int nb = 0; nb < 4; ++nb)
        acc[mb][nb] = __builtin_amdgcn_mfma_f32_16x16x32_bf16(af[mb], bfr[nb], acc[mb][nb], 0, 0, 0);
  }

  const int crow = bm + role * 128 + wm + (quad << 2);
  const int ccol = bn + wn + l16;
  #pragma unroll
  for (int mb = 0; mb < 4; ++mb)
    #pragma unroll
    for (int nb = 0; nb < 4; ++nb)
      #pragma unroll
      for (int r = 0; r < 4; ++r) {
        const long idx = (long)(crow + mb * 16 + r) * N + (ccol + nb * 16);
        out[idx] = acc[mb][nb][r] + res[idx];
      }
}

// ---------- RoPE + layout: qkv bf16 [BT][3072] -> Q [B][NH][T][HD],
//            K [B][NKV][T][HD], V^T [B][NKV][HD][T] ----------
__global__ __launch_bounds__(256) void rope_kernel(
    const bf16* __restrict__ qkv, bf16* __restrict__ Q,
    bf16* __restrict__ K, bf16* __restrict__ VT)
{
  const int t = blockIdx.x, b = blockIdx.y;
  const bf16* row = qkv + (long)(b * T_ + t) * QKVN_;
  const float tf = (float)t;  // positions = t (segment_ids all-ones, cur_ind=0)
  for (int idx = threadIdx.x; idx < NH_ * HD_; idx += 256) {
    const int head = idx >> 7, hd = idx & 127;
    const float v = b2f(row[idx]);
    float o;
    if (hd < 64) {
      const int j = hd & 31;
      const float ang = tf * expf(-(float)j * 0.28782313662425574f); // ln(1e4)/32
      const float sn = sinf(ang), cs = cosf(ang);
      o = (hd < 32) ? (v * cs - b2f(row[idx + 32]) * sn)
                    : (v * cs + b2f(row[idx - 32]) * sn);
    } else o = v;
    Q[((long)(b * NH_ + head) * T_ + t) * HD_ + hd] = f2b(o);
  }
  for (int idx = threadIdx.x; idx < NKV_ * HD_; idx += 256) {
    const int kv = idx >> 7, hd = idx & 127;
    const float v = b2f(row[NH_ * HD_ + idx]);
    float o;
    if (hd < 64) {
      const int j = hd & 31;
      const float ang = tf * expf(-(float)j * 0.28782313662425574f);
      const float sn = sinf(ang), cs = cosf(ang);
      o = (hd < 32) ? (v * cs - b2f(row[NH_ * HD_ + idx + 32]) * sn)
                    : (v * cs + b2f(row[NH_ * HD_ + idx - 32]) * sn);
    } else o = v;
    K[((long)(b * NKV_ + kv) * T_ + t) * HD_ + hd] = f2b(o);
  }
  for (int idx = threadIdx.x; idx < NKV_ * HD_; idx += 256) {
    const int kv = idx >> 7, vd = idx & 127;
    VT[((long)(b * NKV_ + kv) * HD_ + vd) * T_ + t] = row[(NH_ + NKV_) * HD_ + idx];
  }
}

// ---------- Flash attention: 64-row Q tile per block, window 1024, sink ----------
__global__ __launch_bounds__(256) void attn_kernel(
    const bf16* __restrict__ Q, const bf16* __restrict__ Kg,
    const bf16* __restrict__ VTg, const float* __restrict__ sink,
    bf16* __restrict__ attnb)
{
  __shared__ __align__(16) bf16 Qs[64 * 136];   // padded: stride 136 elems (272B)
  __shared__ __align__(16) bf16 Ks[64 * 136];
  __shared__ __align__(16) bf16 Vs[128 * 72];   // V^T tile, stride 72 (144B)
  __shared__ __align__(16) bf16 Ps[64 * 72];    // P round-trip C-layout -> A-layout

  const int qt = blockIdx.x;
  const int bh = blockIdx.y;
  const int b = bh >> 4, h = bh & 15;
  const int kvh = h >> 2;            // GQA: 4 q-heads per kv-head
  const int t0 = qt * 64;
  const int tid = threadIdx.x;
  const int wave = tid >> 6, lane = tid & 63;
  const int quad = lane >> 4, l16 = lane & 15;

  const bf16* Qp = Q + ((long)(b * NH_ + h) * T_ + t0) * HD_;
  #pragma unroll
  for (int c = tid; c < 1024; c += 256) {
    const int r = c >> 4, cc = (c & 15) << 3;
    *(uint4*)&Qs[r * 136 + cc] = *(const uint4*)&Qp[r * HD_ + cc];
  }

  float m_i[4], l_i[4];
  const float sb = sink[h];
  #pragma unroll
  for (int r = 0; r < 4; ++r) { m_i[r] = sb; l_i[r] = 1.0f; }  // sink column
  f32x4 Oacc[8] = {};

  const int st_lo = (qt > 16) ? (qt - 16) : 0;
  for (int st = st_lo; st <= qt; ++st) {
    const int s0 = st * 64;
    __syncthreads();
    const bf16* Kp = Kg + ((long)(b * NKV_ + kvh) * T_ + s0) * HD_;
    #pragma unroll
    for (int c = tid; c < 1024; c += 256) {
      const int r = c >> 4, cc = (c & 15) << 3;
      *(uint4*)&Ks[r * 136 + cc] = *(const uint4*)&Kp[r * HD_ + cc];
    }
    const bf16* Vp = VTg + (long)(b * NKV_ + kvh) * HD_ * T_ + s0;
    #pragma unroll
    for (int c = tid; c < 1024; c += 256) {
      const int r = c >> 3, cc = (c & 7) << 3;
      *(uint4*)&Vs[r * 72 + cc] = *(const uint4*)&Vp[(long)r * T_ + cc];
    }
    __syncthreads();

    // S = Q K^T (each wave: its 16 Q rows x 64 s cols)
    f32x4 sacc[4] = {};
    #pragma unroll
    for (int kb = 0; kb < 4; ++kb) {
      const bf16x8 aq = *(const bf16x8*)&Qs[(wave * 16 + l16) * 136 + kb * 32 + quad * 8];
      #pragma unroll
      for (int nb = 0; nb < 4; ++nb) {
        const bf16x8 bk = *(const bf16x8*)&Ks[(nb * 16 + l16) * 136 + kb * 32 + quad * 8];
        sacc[nb] = __builtin_amdgcn_mfma_f32_16x16x32_bf16(aq, bk, sacc[nb], 0, 0, 0);
      }
    }

    // mask + online softmax (rows live at quad*4+r, cols at l16)
    float sv[4][4];
    float rmax[4] = {-INFINITY, -INFINITY, -INFINITY, -INFINITY};
    const int colb = s0 + l16;
    const int rowb = t0 + wave * 16 + quad * 4;
    #pragma unroll
    for (int nb = 0; nb < 4; ++nb)
      #pragma unroll
      for (int r = 0; r < 4; ++r) {
        float v = sacc[nb][r] * 0.08838834764831845f;  // HD^-0.5
        const int s = colb + nb * 16, tq = rowb + r;
        if (s > tq || s < tq - (WIN_ - 1)) v = -INFINITY;
        sv[nb][r] = v;
        rmax[r] = fmaxf(rmax[r], v);
      }
    #pragma unroll
    for (int r = 0; r < 4; ++r)
      #pragma unroll
      for (int off = 1; off < 16; off <<= 1)
        rmax[r] = fmaxf(rmax[r], __shfl_xor(rmax[r], off, 64));
    float alpha[4], rsum[4];
    #pragma unroll
    for (int r = 0; r < 4; ++r) {
      const float mn = fmaxf(m_i[r], rmax[r]);
      alpha[r] = __expf(m_i[r] - mn);
      m_i[r] = mn;
      rsum[r] = 0.0f;
    }
    #pragma unroll
    for (int nb = 0; nb < 4; ++nb)
      #pragma unroll
      for (int r = 0; r < 4; ++r) {
        const float p = __expf(sv[nb][r] - m_i[r]);   // masked -> exp(-inf)=0
        rsum[r] += p;
        Ps[(wave * 16 + quad * 4 + r) * 72 + nb * 16 + l16] = f2b(p);
      }
    #pragma unroll
    for (int r = 0; r < 4; ++r) {
      #pragma unroll
      for (int off = 1; off < 16; off <<= 1)
        rsum[r] += __shfl_xor(rsum[r], off, 64);
      l_i[r] = l_i[r] * alpha[r] + rsum[r];
    }
    #pragma unroll
    for (int nb = 0; nb < 8; ++nb)
      #pragma unroll
      for (int r = 0; r < 4; ++r)
        Oacc[nb][r] *= alpha[r];
    __syncthreads();  // P visible before A-layout re-read

    // O += P V  (A = P rows of this wave, B = V^T tile)
    #pragma unroll
    for (int ks = 0; ks < 2; ++ks) {
      const bf16x8 ap = *(const bf16x8*)&Ps[(wave * 16 + l16) * 72 + ks * 32 + quad * 8];
      #pragma unroll
      for (int nb = 0; nb < 8; ++nb) {
        const bf16x8 bv = *(const bf16x8*)&Vs[(nb * 16 + l16) * 72 + ks * 32 + quad * 8];
        Oacc[nb] = __builtin_amdgcn_mfma_f32_16x16x32_bf16(ap, bv, Oacc[nb], 0, 0, 0);
      }
    }
  }

  float rcp[4];
  #pragma unroll
  for (int r = 0; r < 4; ++r) rcp[r] = 1.0f / l_i[r];
  bf16* outp = attnb + ((long)(b * T_ + t0 + wave * 16 + quad * 4)) * EMB_ + h * HD_ + l16;
  #pragma unroll
  for (int nb = 0; nb < 8; ++nb)
    #pragma unroll
    for (int r = 0; r < 4; ++r)
      outp[(long)r * EMB_ + nb * 16] = f2b(Oacc[nb][r] * rcp[r]);
}

extern "C" void kernel_launch(void* const* d_in, const int* in_sizes, int n_in,
                              void* d_out, int out_size, void* d_ws, size_t ws_size,
                              hipStream_t stream)
{
  (void)in_sizes; (void)n_in; (void)out_size; (void)ws_size;
  const float* x    = (const float*)d_in[0];
  const float* wq   = (const float*)d_in[2];
  const float* wk   = (const float*)d_in[3];
  const float* wv   = (const float*)d_in[4];
  const float* wo   = (const float*)d_in[5];
  const float* sink = (const float*)d_in[6];
  const float* gw   = (const float*)d_in[7];
  const float* uw   = (const float*)d_in[8];
  const float* dw   = (const float*)d_in[9];
  const float* n1   = (const float*)d_in[10];
  const float* n2   = (const float*)d_in[11];

  // ---- workspace: 184.5 MB via phase aliasing ----
  char* base = (char*)d_ws;
  bf16*  hbuf  = (bf16*)base;                                   // 16,777,216
  char*  R1    = base + (size_t)16777216;                       // 67,108,864
  char*  R2    = R1   + (size_t)67108864;                       // 33,554,432
  bf16*  mact  = (bf16*)(R2 + (size_t)33554432);                // 67,108,864

  // phase A views
  bf16* qkv   = (bf16*)R1;                                      // 25,165,824
  bf16* Qb    = (bf16*)(R1 + 25165824);                         // 16,777,216
  bf16* Kb    = (bf16*)(R1 + 41943040);                         //  4,194,304
  bf16* VTb   = (bf16*)(R1 + 46137344);                         //  4,194,304
  bf16* attnb = (bf16*)R1;            // aliases qkv (dead after rope)
  bf16* wqkvT = (bf16*)R2;                                      // 12,582,912
  bf16* woT   = (bf16*)(R2 + 12582912);                         //  8,388,608
  // phase B views
  bf16* gateT = (bf16*)R1;                                      // 33,554,432
  bf16* upT   = (bf16*)(R1 + 33554432);                         // 33,554,432
  bf16* downT = (bf16*)R2;                                      // 33,554,432
  float* x1   = (float*)d_out;        // residual after attention

  const dim3 tb(32, 8);
  // ---- phase A: attention ----
  transpose_kernel<<<dim3( 64,  64), tb, 0, stream>>>(wq, wqkvT,                      EMB_, EMB_);
  transpose_kernel<<<dim3( 16,  64), tb, 0, stream>>>(wk, wqkvT + (size_t)2048*EMB_,  EMB_, 512);
  transpose_kernel<<<dim3( 16,  64), tb, 0, stream>>>(wv, wqkvT + (size_t)2560*EMB_,  EMB_, 512);
  transpose_kernel<<<dim3( 64,  64), tb, 0, stream>>>(wo, woT,                        EMB_, EMB_);

  rmsnorm_kernel<<<BT_, 256, 0, stream>>>(x, n1, hbuf);
  gemm_kernel<0><<<dim3(QKVN_/128, BT_/128), 256, 0, stream>>>(hbuf, wqkvT, qkv, nullptr, BT_, QKVN_, EMB_);
  rope_kernel<<<dim3(T_, B_), 256, 0, stream>>>(qkv, Qb, Kb, VTb);
  attn_kernel<<<dim3(T_/64, B_*NH_), 256, 0, stream>>>(Qb, Kb, VTb, sink, attnb);
  gemm_kernel<1><<<dim3(EMB_/128, BT_/128), 256, 0, stream>>>(attnb, woT, x1, x, BT_, EMB_, EMB_);

  // ---- phase B: MLP ----
  rmsnorm_kernel<<<BT_, 256, 0, stream>>>(x1, n2, hbuf);
  transpose_kernel<<<dim3(256,  64), tb, 0, stream>>>(gw, gateT, EMB_, MLPD_);
  transpose_kernel<<<dim3(256,  64), tb, 0, stream>>>(uw, upT,   EMB_, MLPD_);
  mlp_gateup_kernel<<<dim3(MLPD_/128, BT_/128), 512, 0, stream>>>(hbuf, gateT, upT, mact, BT_, MLPD_, EMB_);
  transpose_kernel<<<dim3( 64, 256), tb, 0, stream>>>(dw, downT, MLPD_, EMB_);
  down_kernel<<<dim3(EMB_/128, BT_/256), 512, 0, stream>>>(mact, downT, (float*)d_out, x1, BT_, EMB_, MLPD_);
}